// Round 1
// baseline (600.893 us; speedup 1.0000x reference)
//
#include <hip/hip_runtime.h>
#include <stdint.h>

// CrossAttention on MI355X (gfx950). fp32 I/O, bf16 MFMA compute.
// Round 6: replace 128x128 / 2-barrier GEMM with the 256x256 8-phase
// schedule (T3+T4 counted-vmcnt pipeline, T5 setprio, raw s_barrier).
// 8 waves (2M x 4N, interleaved row/col ownership), BK=64 double-buffered
// in 128 KiB LDS, one half-tile (128 rows x 64k) staged per phase,
// s_waitcnt vmcnt(4) only at phases 3 and 7. XOR-chunk LDS swizzle and
// staging/fragment/epilogue addressing carried over from the verified
// 128x128 kernel (bank conflicts measured 0).
// Schedule: cvt -> Wt -> PROJx6 -> S1+S2 -> softmax(both)+copy -> O1+O2.
// Peak ws 171.97 MB (unchanged).

typedef unsigned short u16;
typedef __attribute__((ext_vector_type(8))) __bf16 bf16x8;
typedef __attribute__((ext_vector_type(4))) float f32x4;

__device__ __forceinline__ float bf2f(u16 u) {
  union { unsigned int i; float f; } x; x.i = ((unsigned int)u) << 16; return x.f;
}
__device__ __forceinline__ u16 f2bf(float f) {  // RNE
  union { float f; unsigned int i; } x; x.f = f;
  unsigned int i = x.i;
  i += 0x7fffu + ((i >> 16) & 1u);
  return (u16)(i >> 16);
}

// async global->LDS, 16B per lane. LDS dest is wave-uniform base + lane*16.
__device__ __forceinline__ void cp16(void* lds, const void* g) {
  __builtin_amdgcn_global_load_lds((__attribute__((address_space(1))) void*)g,
                                   (__attribute__((address_space(3))) void*)lds,
                                   16, 0, 0);
}

// ---------------------------------------------------------------------------
// Multi-GEMM, 256x256 tile, BK=64, 8 waves, 8-phase counted-vmcnt pipeline.
// C = scale*A.Bt^T (+bias); bf16/fp32 out.
// LDS rows = 64 elems (128 B, 8 chunks of 16 B); chunk c of row m stored at
// c ^ (m&7) (measured conflict-free). Staging keeps wave-uniform base +
// lane*16 (global side permuted within the row).
// Wave (wm,wn) owns C rows {wm*64..+64} u {128+wm*64..+64} and cols
// {wn*32..+32} u {128+wn*32..+32}; phase (mh,nh) computes one quadrant so
// each A/B half-slot is read in exactly 2 of 4 phases -> half-tile-granular
// re-staging with 2 LDS buffers.
// ---------------------------------------------------------------------------
struct GemmDesc {
  const u16* A; const u16* Bt; const float* bias; void* C;
  long sA, sB, sC;          // batch strides (elements)
  int K, lda, ldb, ldc;
  int gx, gy;
  int start;
  int mode, outf;           // bias: 0 none/1 col/2 row; out: 0 bf16, 1 fp32
  float scale;
};
struct GemmPack { GemmDesc d[6]; int nd; };

// One phase: 12 ds_read_b128 (next quadrant) || 1 half-tile stage issue ->
// s_barrier -> lgkmcnt(0) (pins LDS reads complete before the closing
// barrier, so re-staging a slot next phase is race-free) -> setprio(1) ->
// 16 MFMA -> setprio(0) -> [counted vmcnt] -> s_barrier.
#define PHASE(MH, NH, PAR, STAGE, WAITC)                                      \
  {                                                                           \
    const bf16x8* As8 =                                                       \
        (const bf16x8*)((const char*)L + (PAR) * 32768 + (MH) * 16384);       \
    const bf16x8* Bs8 =                                                       \
        (const bf16x8*)((const char*)L + 65536 + (PAR) * 32768 + (NH) * 16384);\
    bf16x8 a0[2][4], b0[2][2];                                                \
    _Pragma("unroll")                                                         \
    for (int s = 0; s < 2; ++s) {                                             \
      _Pragma("unroll")                                                       \
      for (int i = 0; i < 4; ++i) a0[s][i] = As8[iaq[s][i]];                  \
      _Pragma("unroll")                                                       \
      for (int j = 0; j < 2; ++j) b0[s][j] = Bs8[ibq[s][j]];                  \
    }                                                                         \
    STAGE;                                                                    \
    __builtin_amdgcn_s_barrier();                                             \
    asm volatile("s_waitcnt lgkmcnt(0)" ::: "memory");                        \
    __builtin_amdgcn_s_setprio(1);                                            \
    _Pragma("unroll")                                                         \
    for (int s = 0; s < 2; ++s)                                               \
      _Pragma("unroll")                                                       \
      for (int i = 0; i < 4; ++i)                                             \
        _Pragma("unroll")                                                     \
        for (int j = 0; j < 2; ++j)                                           \
          acc[MH][NH][i][j] = __builtin_amdgcn_mfma_f32_16x16x32_bf16(        \
              b0[s][j], a0[s][i], acc[MH][NH][i][j], 0, 0, 0);                \
    __builtin_amdgcn_s_setprio(0);                                            \
    WAITC;                                                                    \
    __builtin_amdgcn_s_barrier();                                             \
  }

__global__ __launch_bounds__(512, 2)
void gemm256_kernel(GemmPack p)
{
  __shared__ __align__(16) u16 L[65536];   // A: 2x32KB, B: 2x32KB = 128 KB

  int seg = 0;
#pragma unroll
  for (int t = 1; t < 6; ++t)
    if (t < p.nd && (int)blockIdx.x >= p.d[t].start) seg = t;
  const GemmDesc& g = p.d[seg];
  const int local = (int)blockIdx.x - g.start;
  const int pxy = g.gx * g.gy;
  const int bz = local / pxy;
  const int rem = local - bz * pxy;
  const int by = rem / g.gx;
  const int bx = rem - by * g.gx;

  const int tid  = threadIdx.x;
  const int lane = tid & 63;
  const int wave = tid >> 6;
  const int l15  = lane & 15;
  const int quad = lane >> 4;
  const int wm   = wave >> 2;   // 0..1  (row-group owner)
  const int wn   = wave & 3;    // 0..3  (col-group owner)

  const char* Ab = (const char*)(g.A + (long)bz * g.sA + (long)bx * 256 * g.lda);
  const char* Bb = (const char*)(g.Bt + (long)bz * g.sB + (long)by * 256 * g.ldb);
  const long ldaB = (long)g.lda * 2;
  const long ldbB = (long)g.ldb * 2;

  // Staging: one half-tile = 128 rows x 64k = 16 KB = 2 x (512 thr x 16 B).
  // Load li covers rows [li*64 + wave*8 + (lane>>3)); lds chunk = lane&7,
  // global chunk = (lane&7) ^ (row&7), row&7 = lane>>3.
  const int gchk = (lane & 7) ^ (lane >> 3);
  const char* pa0 = Ab + (long)(wave * 8 + (lane >> 3)) * ldaB + (gchk << 4);
  const char* pb0 = Bb + (long)(wave * 8 + (lane >> 3)) * ldbB + (gchk << 4);
  char* lA = (char*)L + wave * 1024;
  char* lB = (char*)L + 65536 + wave * 1024;

  auto stageA = [&](int par, int h, int kt) {
    char* d = lA + par * 32768 + h * 16384;
    const char* s = pa0 + (long)h * 128 * ldaB + ((long)kt << 7);
    cp16(d, s);
    cp16(d + 8192, s + 64 * ldaB);
  };
  auto stageB = [&](int par, int h, int kt) {
    char* d = lB + par * 32768 + h * 16384;
    const char* s = pb0 + (long)h * 128 * ldbB + ((long)kt << 7);
    cp16(d, s);
    cp16(d + 8192, s + 64 * ldbB);
  };

  // Fragment LDS indices within a 128-row half (bf16x8 units): row m,
  // k-step s: idx = m*8 + ((s*4+quad) ^ (m&7)), m&7 = l15&7.
  int iaq[2][4], ibq[2][2];
#pragma unroll
  for (int s = 0; s < 2; ++s) {
#pragma unroll
    for (int i = 0; i < 4; ++i)
      iaq[s][i] = (wm * 64 + i * 16 + l15) * 8 + ((s * 4 + quad) ^ (l15 & 7));
#pragma unroll
    for (int j = 0; j < 2; ++j)
      ibq[s][j] = (wn * 32 + j * 16 + l15) * 8 + ((s * 4 + quad) ^ (l15 & 7));
  }

  f32x4 acc[2][2][4][2];
  {
    f32x4 zz = {0.f, 0.f, 0.f, 0.f};
#pragma unroll
    for (int mh = 0; mh < 2; ++mh)
#pragma unroll
      for (int nh = 0; nh < 2; ++nh)
#pragma unroll
        for (int i = 0; i < 4; ++i)
#pragma unroll
          for (int j = 0; j < 2; ++j) acc[mh][nh][i][j] = zz;
  }

  // Prologue: tile0 all 4 halves + tile1 lows; wait tile0, keep lows in flight.
  stageA(0, 0, 0); stageB(0, 0, 0);
  stageA(0, 1, 0); stageB(0, 1, 0);
  stageA(1, 0, 1); stageB(1, 0, 1);
  asm volatile("s_waitcnt vmcnt(4)" ::: "memory");
  __builtin_amdgcn_s_barrier();

  // Steady state per iteration (tiles t=2it -> buf0, t+1 -> buf1):
  //   ph0: q(0,0) t   | stage A-high(t+1)        ph4: q(0,0) t+1 | A-high(t+2)
  //   ph1: q(0,1) t   | stage B-high(t+1)        ph5: q(0,1) t+1 | B-high(t+2)
  //   ph2: q(1,0) t   | stage A-low (t+2)        ph6: q(1,0) t+1 | A-low (t+3)
  //   ph3: q(1,1) t   | B-low(t+2), vmcnt(4)     ph7: q(1,1) t+1 | B-low (t+3), vmcnt(4)
  // vmcnt(4) at ph3 completes all of tile t+1 (leaves lows(t+2) in flight);
  // at ph7 completes all of tile t+2 (leaves lows(t+3)).
  const int NI = g.K >> 7;   // K-tile pairs; all K here are multiples of 128
  for (int it = 0; it < NI; ++it) {
    const int t = it * 2;
    const bool more = (it + 1) < NI;
    PHASE(0, 0, 0, stageA(1, 1, t + 1), )
    PHASE(0, 1, 0, stageB(1, 1, t + 1), )
    PHASE(1, 0, 0, if (more) stageA(0, 0, t + 2), )
    PHASE(1, 1, 0, if (more) stageB(0, 0, t + 2),
          if (more) { asm volatile("s_waitcnt vmcnt(4)" ::: "memory"); }
          else      { asm volatile("s_waitcnt vmcnt(0)" ::: "memory"); })
    PHASE(0, 0, 1, if (more) stageA(0, 1, t + 2), )
    PHASE(0, 1, 1, if (more) stageB(0, 1, t + 2), )
    PHASE(1, 0, 1, if (more) stageA(1, 0, t + 3), )
    PHASE(1, 1, 1, if (more) stageB(1, 0, t + 3),
          if (more) { asm volatile("s_waitcnt vmcnt(4)" ::: "memory"); })
  }

  // Epilogue (swapped-operand layout): lane l15 = C row, regs = 4 cols.
  const long cbase = (long)bz * g.sC;
#pragma unroll
  for (int mh = 0; mh < 2; ++mh) {
#pragma unroll
    for (int i = 0; i < 4; ++i) {
      const int row = bx * 256 + mh * 128 + wm * 64 + i * 16 + l15;
      const float rbias = (g.mode == 2) ? g.bias[row] : 0.f;
#pragma unroll
      for (int nh = 0; nh < 2; ++nh) {
#pragma unroll
        for (int j = 0; j < 2; ++j) {
          const int colbase = by * 256 + nh * 128 + wn * 32 + j * 16 + quad * 4;
          float v[4];
#pragma unroll
          for (int r = 0; r < 4; ++r) v[r] = acc[mh][nh][i][j][r] * g.scale;
          if (g.mode == 1) {
            const float4 cb = *(const float4*)(g.bias + colbase);
            v[0] += cb.x; v[1] += cb.y; v[2] += cb.z; v[3] += cb.w;
          } else if (g.mode == 2) {
#pragma unroll
            for (int r = 0; r < 4; ++r) v[r] += rbias;
          }
          const long idx = cbase + (long)row * g.ldc + colbase;
          if (g.outf) {
            float4 st; st.x = v[0]; st.y = v[1]; st.z = v[2]; st.w = v[3];
            *(float4*)((float*)g.C + idx) = st;
          } else {
            uint2 st;
            st.x = (unsigned int)f2bf(v[0]) | ((unsigned int)f2bf(v[1]) << 16);
            st.y = (unsigned int)f2bf(v[2]) | ((unsigned int)f2bf(v[3]) << 16);
            *(uint2*)((u16*)g.C + idx) = st;
          }
        }
      }
    }
  }
}

// ---------------------------------------------------------------------------
// fp32 -> bf16 convert for two tensors in one launch. 8 elems/thread.
// ---------------------------------------------------------------------------
__global__ __launch_bounds__(256)
void cvt2_bf16_kernel(const float* __restrict__ sa, u16* __restrict__ da, int n8a,
                      const float* __restrict__ sb, u16* __restrict__ db, int n8b)
{
  int idx = blockIdx.x * 256 + threadIdx.x;
  const float* src; u16* dst; int i;
  if (idx < n8a) { src = sa; dst = da; i = idx; }
  else           { src = sb; dst = db; i = idx - n8a; if (i >= n8b) return; }
  const float4* s4 = (const float4*)src;
  float4 a = s4[i * 2], b = s4[i * 2 + 1];
  uint4 o;
  o.x = (unsigned int)f2bf(a.x) | ((unsigned int)f2bf(a.y) << 16);
  o.y = (unsigned int)f2bf(a.z) | ((unsigned int)f2bf(a.w) << 16);
  o.z = (unsigned int)f2bf(b.x) | ((unsigned int)f2bf(b.y) << 16);
  o.w = (unsigned int)f2bf(b.z) | ((unsigned int)f2bf(b.w) << 16);
  ((uint4*)dst)[i] = o;
}

// ---------------------------------------------------------------------------
// Transpose + convert six 768x768 fp32 weights ([in,out] -> bf16 [out,in]).
// ---------------------------------------------------------------------------
__global__ void transpose6_kernel(const float* s0, const float* s1, const float* s2,
                                  const float* s3, const float* s4, const float* s5,
                                  u16* d0, u16* d1, u16* d2,
                                  u16* d3, u16* d4, u16* d5)
{
  __shared__ float t[32][33];
  const float* src; u16* dst;
  switch (blockIdx.z) {
    case 0: src = s0; dst = d0; break;
    case 1: src = s1; dst = d1; break;
    case 2: src = s2; dst = d2; break;
    case 3: src = s3; dst = d3; break;
    case 4: src = s4; dst = d4; break;
    default: src = s5; dst = d5; break;
  }
  const int tx = threadIdx.x, ty = threadIdx.y;
  const int x = blockIdx.x * 32 + tx;
  const int y0 = blockIdx.y * 32;
#pragma unroll
  for (int j = 0; j < 32; j += 8) t[ty + j][tx] = src[(long)(y0 + ty + j) * 768 + x];
  __syncthreads();
  const int x2 = y0 + tx;
#pragma unroll
  for (int j = 0; j < 32; j += 8)
    dst[(long)(blockIdx.x * 32 + ty + j) * 768 + x2] = f2bf(t[tx][ty + j]);
}

// ---------------------------------------------------------------------------
// In-place row softmax (bf16) over S1 rows (4096 wide, 8192 rows) and S2 rows
// (2048 wide, 16384 rows), plus V2T evacuation copy, all in one launch.
// ---------------------------------------------------------------------------
template <int NV>
__device__ __forceinline__ void softmax_row(u16* row)
{
  __shared__ float red[8];
  const int tid  = threadIdx.x;
  const int lane = tid & 63;
  const int wave = tid >> 6;
  uint4* p4 = (uint4*)row;

  uint4 ld[NV / 8];
#pragma unroll
  for (int c = 0; c < NV / 8; ++c) ld[c] = p4[tid + c * 256];
  float v[NV];
#pragma unroll
  for (int c = 0; c < NV / 8; ++c) {
    unsigned int w[4] = {ld[c].x, ld[c].y, ld[c].z, ld[c].w};
#pragma unroll
    for (int q = 0; q < 4; ++q) {
      v[c * 8 + q * 2]     = bf2f((u16)(w[q] & 0xffffu));
      v[c * 8 + q * 2 + 1] = bf2f((u16)(w[q] >> 16));
    }
  }

  float m = -1e30f;
#pragma unroll
  for (int i = 0; i < NV; ++i) m = fmaxf(m, v[i]);
#pragma unroll
  for (int off = 32; off > 0; off >>= 1) m = fmaxf(m, __shfl_xor(m, off, 64));
  if (lane == 0) red[wave] = m;
  __syncthreads();
  m = fmaxf(fmaxf(red[0], red[1]), fmaxf(red[2], red[3]));

  float s = 0.f;
#pragma unroll
  for (int i = 0; i < NV; ++i) { v[i] = __expf(v[i] - m); s += v[i]; }
#pragma unroll
  for (int off = 32; off > 0; off >>= 1) s += __shfl_xor(s, off, 64);
  if (lane == 0) red[4 + wave] = s;
  __syncthreads();
  s = (red[4] + red[5]) + (red[6] + red[7]);
  const float inv = 1.0f / s;

#pragma unroll
  for (int c = 0; c < NV / 8; ++c) {
    unsigned int w[4];
#pragma unroll
    for (int q = 0; q < 4; ++q) {
      const u16 lo = f2bf(v[c * 8 + q * 2] * inv);
      const u16 hi = f2bf(v[c * 8 + q * 2 + 1] * inv);
      w[q] = (unsigned int)lo | ((unsigned int)hi << 16);
    }
    uint4 st; st.x = w[0]; st.y = w[1]; st.z = w[2]; st.w = w[3];
    p4[tid + c * 256] = st;
  }
}

__global__ __launch_bounds__(256)
void softmax_both_kernel(u16* S1, u16* S2, const u16* cpy_src, u16* cpy_dst)
{
  if (blockIdx.x < 8192) { softmax_row<16>(S1 + (long)blockIdx.x * 4096); return; }
  if (blockIdx.x < 24576) { softmax_row<8>(S2 + (long)(blockIdx.x - 8192) * 2048); return; }
  // copy blocks: 1536 blocks x 8 KB = 12,582,912 B (V2T out of out1)
  const long base = (long)(blockIdx.x - 24576) * 512 + threadIdx.x;
  const uint4* s = (const uint4*)cpy_src;
  uint4* d = (uint4*)cpy_dst;
  d[base] = s[base];
  d[base + 256] = s[base + 256];
}

// ---------------------------------------------------------------------------

static GemmDesc mkdesc(const void* A, const void* Bt, const float* bias, void* C,
                       long sA, long sB, long sC, int K, int lda, int ldb, int ldc,
                       int M, int N, int start, int mode, int outf, float scale)
{
  GemmDesc d;
  d.A = (const u16*)A; d.Bt = (const u16*)Bt; d.bias = bias; d.C = C;
  d.sA = sA; d.sB = sB; d.sC = sC;
  d.K = K; d.lda = lda; d.ldb = ldb; d.ldc = ldc;
  d.gx = M / 256; d.gy = N / 256; d.start = start;
  d.mode = mode; d.outf = outf; d.scale = scale;
  return d;
}

extern "C" void kernel_launch(void* const* d_in, const int* in_sizes, int n_in,
                              void* d_out, int out_size, void* d_ws, size_t ws_size,
                              hipStream_t stream)
{
  (void)in_sizes; (void)n_in; (void)out_size; (void)ws_size;
  const float* syn = (const float*)d_in[0];   // [4,4096,768] fp32
  const float* sem = (const float*)d_in[1];   // [4,2048,768] fp32
  const float* W[6]    = {(const float*)d_in[2], (const float*)d_in[4],  (const float*)d_in[6],
                          (const float*)d_in[8], (const float*)d_in[10], (const float*)d_in[12]};
  const float* bias[6] = {(const float*)d_in[3], (const float*)d_in[5],  (const float*)d_in[7],
                          (const float*)d_in[9], (const float*)d_in[11], (const float*)d_in[13]};
  float* out = (float*)d_out;

  // ws arena (u16 offsets). Peak use 85,983,232 u16 = 171.97 MB.
  u16* ws   = (u16*)d_ws;
  u16* S1   = ws;                       // [0, 33,554,432)
  u16* synb = ws;                       //   [0, 12,582,912)   dead after PROJ
  u16* semb = ws + 12582912;            //   [.., 18,874,368)  dead after PROJ
  u16* WT   = ws + 18874368;            //   [.., 22,413,312)  dead after PROJ
  u16* S2   = ws + 33554432;            // [.., 67,108,864)
  u16* V1T  = ws + 67108864;            // [.., 79,691,776)    until O1
  u16* Q1   = ws + 79691776;            // [.., 85,983,232)    dead after S1
  u16* V2Tc = ws + 79691776;            //   V2T copy target (over dead Q1)
  // parked in outputs:
  u16* K1  = (u16*)out;                 // out0: 12,582,912 u16, dead after S1
  u16* o1  = (u16*)(out + 6291456);     // out1 region base
  u16* Q2  = o1;                        // 12,582,912 u16, dead after S2
  u16* K2  = o1 + 12582912;             //  6,291,456 u16, dead after S2
  u16* V2T = o1 + 18874368;             //  6,291,456 u16, evacuated in D5

  const float SC = 0.036084391824351615f;  // 768^-0.5

  // D1) fp32 -> bf16 converts
  cvt2_bf16_kernel<<<dim3(9216), dim3(256), 0, stream>>>(
      syn, synb, 1572864, sem, semb, 786432);

  // D2) weight transpose+convert
  transpose6_kernel<<<dim3(24, 24, 6), dim3(32, 8, 1), 0, stream>>>(
      W[0], W[1], W[2], W[3], W[4], W[5],
      WT + 0 * 589824, WT + 1 * 589824, WT + 2 * 589824,
      WT + 3 * 589824, WT + 4 * 589824, WT + 5 * 589824);

  // D3) all six projections (864 blocks @ 256^2)
  {
    GemmPack p; p.nd = 6;
    p.d[0] = mkdesc(synb, WT + 1 * 589824, bias[1], K1, 0, 0, 0,     // K1 -> out0
                    768, 768, 768, 768, 16384, 768, 0, 1, 0, 1.f);
    p.d[1] = mkdesc(synb, WT + 3 * 589824, bias[3], Q2, 0, 0, 0,     // Q2 -> out1
                    768, 768, 768, 768, 16384, 768, 192, 1, 0, 1.f);
    p.d[2] = mkdesc(WT + 2 * 589824, synb, bias[2], V1T, 0, 0, 0,    // V1T -> ws
                    768, 768, 768, 16384, 768, 16384, 384, 2, 0, 1.f);
    p.d[3] = mkdesc(semb, WT + 0 * 589824, bias[0], Q1, 0, 0, 0,     // Q1 -> ws
                    768, 768, 768, 768, 8192, 768, 576, 1, 0, 1.f);
    p.d[4] = mkdesc(semb, WT + 4 * 589824, bias[4], K2, 0, 0, 0,     // K2 -> out1
                    768, 768, 768, 768, 8192, 768, 672, 1, 0, 1.f);
    p.d[5] = mkdesc(WT + 5 * 589824, semb, bias[5], V2T, 0, 0, 0,    // V2T -> out1
                    768, 768, 768, 8192, 768, 8192, 768, 2, 0, 1.f);
    gemm256_kernel<<<dim3(864), dim3(512), 0, stream>>>(p);
  }

  // D4) S1 + S2 (1024 blocks @ 256^2); S1 overwrites dead synb/semb/WT
  {
    GemmPack p; p.nd = 2;
    p.d[0] = mkdesc(Q1, K1, nullptr, S1,                             // [4][2048x4096]
                    1572864L, 3145728L, 8388608L,
                    768, 768, 768, 4096, 2048, 4096, 0, 0, 0, SC);
    p.d[1] = mkdesc(Q2, K2, nullptr, S2,                             // [4][4096x2048]
                    3145728L, 1572864L, 8388608L,
                    768, 768, 768, 2048, 4096, 2048, 512, 0, 0, SC);
    gemm256_kernel<<<dim3(1024), dim3(512), 0, stream>>>(p);
  }

  // D5) softmax over all S rows + V2T evacuation (one launch)
  softmax_both_kernel<<<dim3(26112), dim3(256), 0, stream>>>(S1, S2, V2T, V2Tc);

  // D6) O1 + O2 (288 blocks @ 256^2), fp32 -> d_out; long O1 blocks first
  {
    GemmPack p; p.nd = 2;
    p.d[0] = mkdesc(S1, V1T, nullptr, out,                           // [4][2048x768]
                    8388608L, 4096L, 1572864L,
                    4096, 4096, 16384, 768, 2048, 768, 0, 0, 1, 1.f);
    p.d[1] = mkdesc(S2, V2Tc, nullptr, out + 6291456,                // [4][4096x768]
                    8388608L, 2048L, 3145728L,
                    2048, 2048, 8192, 768, 4096, 768, 96, 0, 1, 1.f);
    gemm256_kernel<<<dim3(288), dim3(512), 0, stream>>>(p);
  }
}

// Round 2
// 566.322 us; speedup vs baseline: 1.0610x; 1.0610x over previous
//
#include <hip/hip_runtime.h>
#include <stdint.h>

// CrossAttention on MI355X (gfx950). fp32 I/O, bf16 MFMA compute.
// Round 7: fix the 8-phase schedule's LDS oversubscription. Phases now walk
// row-quarters at FULL column width: B fragments are read once per K-tile
// (ph0/ph4, 12 ds_read_b128) and held in registers across 4 phases; ph1-3
// read only 4 A fragments. LDS traffic/iter halves (96 -> 48 b128 reads),
// putting MFMA (512 cyc/phase/CU) above LDS (384) as the critical pipe.
// Stage ledger: Ah(t+1)@ph0, Bl(t+2)@ph1, Bh(t+2)@ph2, Al(t+2)@ph3+vmcnt(6),
// Ah(t+2)@ph4, Bl/Bh/Al(t+3)@ph5-7+vmcnt(6). Addressing/swizzle/epilogue
// identical to the verified round-6 kernel.
// Schedule: cvt -> Wt -> PROJx6 -> S1+S2 -> softmax(both)+copy -> O1+O2.
// Peak ws 171.97 MB (unchanged).

typedef unsigned short u16;
typedef __attribute__((ext_vector_type(8))) __bf16 bf16x8;
typedef __attribute__((ext_vector_type(4))) float f32x4;

__device__ __forceinline__ float bf2f(u16 u) {
  union { unsigned int i; float f; } x; x.i = ((unsigned int)u) << 16; return x.f;
}
__device__ __forceinline__ u16 f2bf(float f) {  // RNE
  union { float f; unsigned int i; } x; x.f = f;
  unsigned int i = x.i;
  i += 0x7fffu + ((i >> 16) & 1u);
  return (u16)(i >> 16);
}

// async global->LDS, 16B per lane. LDS dest is wave-uniform base + lane*16.
__device__ __forceinline__ void cp16(void* lds, const void* g) {
  __builtin_amdgcn_global_load_lds((__attribute__((address_space(1))) void*)g,
                                   (__attribute__((address_space(3))) void*)lds,
                                   16, 0, 0);
}

// ---------------------------------------------------------------------------
// Multi-GEMM, 256x256 tile, BK=64, 8 waves, 8-phase counted-vmcnt pipeline.
// C = scale*A.Bt^T (+bias); bf16/fp32 out.
// LDS rows = 64 elems (128 B, 8 chunks of 16 B); chunk c of row m stored at
// c ^ (m&7) (measured conflict-free). Staging keeps wave-uniform base +
// lane*16 (global side permuted within the row).
// Wave (wm,wn) owns C rows {wm*64..+64} u {128+wm*64..+64} and cols
// {wn*32..+32} u {128+wn*32..+32}. Phase p computes row-quarter p (32 rows)
// at full 64-col width x K=64: A-low read ph0-1, A-high ph2-3, B read once
// at ph0 and held in bfr[] across the K-tile.
// ---------------------------------------------------------------------------
struct GemmDesc {
  const u16* A; const u16* Bt; const float* bias; void* C;
  long sA, sB, sC;          // batch strides (elements)
  int K, lda, ldb, ldc;
  int gx, gy;
  int start;
  int mode, outf;           // bias: 0 none/1 col/2 row; out: 0 bf16, 1 fp32
  float scale;
};
struct GemmPack { GemmDesc d[6]; int nd; };

// One phase: {4 A ds_read (+8 B ds_read if RDB)} || 1 half-tile stage issue
// -> [lgkmcnt(8) if RDB] -> s_barrier -> lgkmcnt(0) -> setprio(1) -> 16 MFMA
// -> setprio(0) -> [counted vmcnt] -> s_barrier.
#define PHASE(MH, I0, PAR, RDB, STAGE, WAITC)                                 \
  {                                                                           \
    const bf16x8* As8 =                                                       \
        (const bf16x8*)((const char*)L + (PAR) * 32768 + (MH) * 16384);       \
    bf16x8 a0[2][2];                                                          \
    _Pragma("unroll")                                                         \
    for (int s = 0; s < 2; ++s)                                               \
      _Pragma("unroll")                                                       \
      for (int i = 0; i < 2; ++i) a0[s][i] = As8[iaq[s][(I0) + i]];           \
    if (RDB) {                                                                \
      const bf16x8* Bl8 =                                                     \
          (const bf16x8*)((const char*)L + 65536 + (PAR) * 32768);            \
      const bf16x8* Bh8 =                                                     \
          (const bf16x8*)((const char*)L + 65536 + (PAR) * 32768 + 16384);    \
      _Pragma("unroll")                                                       \
      for (int s = 0; s < 2; ++s)                                             \
        _Pragma("unroll")                                                     \
        for (int j = 0; j < 2; ++j) {                                         \
          bfr[0][s][j] = Bl8[ibq[s][j]];                                      \
          bfr[1][s][j] = Bh8[ibq[s][j]];                                      \
        }                                                                     \
    }                                                                         \
    STAGE;                                                                    \
    if (RDB) { asm volatile("s_waitcnt lgkmcnt(8)" ::: "memory"); }           \
    __builtin_amdgcn_s_barrier();                                             \
    asm volatile("s_waitcnt lgkmcnt(0)" ::: "memory");                        \
    __builtin_amdgcn_s_setprio(1);                                            \
    _Pragma("unroll")                                                         \
    for (int s = 0; s < 2; ++s)                                               \
      _Pragma("unroll")                                                       \
      for (int i = 0; i < 2; ++i)                                             \
        _Pragma("unroll")                                                     \
        for (int nh = 0; nh < 2; ++nh)                                        \
          _Pragma("unroll")                                                   \
          for (int j = 0; j < 2; ++j)                                         \
            acc[MH][nh][(I0) + i][j] =                                        \
                __builtin_amdgcn_mfma_f32_16x16x32_bf16(                      \
                    bfr[nh][s][j], a0[s][i], acc[MH][nh][(I0) + i][j],        \
                    0, 0, 0);                                                 \
    __builtin_amdgcn_s_setprio(0);                                            \
    WAITC;                                                                    \
    __builtin_amdgcn_s_barrier();                                             \
  }

__global__ __launch_bounds__(512, 2)
void gemm256_kernel(GemmPack p)
{
  __shared__ __align__(16) u16 L[65536];   // A: 2x32KB, B: 2x32KB = 128 KB

  int seg = 0;
#pragma unroll
  for (int t = 1; t < 6; ++t)
    if (t < p.nd && (int)blockIdx.x >= p.d[t].start) seg = t;
  const GemmDesc& g = p.d[seg];
  const int local = (int)blockIdx.x - g.start;
  const int pxy = g.gx * g.gy;
  const int bz = local / pxy;
  const int rem = local - bz * pxy;
  const int by = rem / g.gx;
  const int bx = rem - by * g.gx;

  const int tid  = threadIdx.x;
  const int lane = tid & 63;
  const int wave = tid >> 6;
  const int l15  = lane & 15;
  const int quad = lane >> 4;
  const int wm   = wave >> 2;   // 0..1  (row-group owner)
  const int wn   = wave & 3;    // 0..3  (col-group owner)

  const char* Ab = (const char*)(g.A + (long)bz * g.sA + (long)bx * 256 * g.lda);
  const char* Bb = (const char*)(g.Bt + (long)bz * g.sB + (long)by * 256 * g.ldb);
  const long ldaB = (long)g.lda * 2;
  const long ldbB = (long)g.ldb * 2;

  // Staging: one half-tile = 128 rows x 64k = 16 KB = 2 x (512 thr x 16 B).
  // lds chunk = lane&7, global chunk = (lane&7) ^ (row&7), row&7 = lane>>3.
  const int gchk = (lane & 7) ^ (lane >> 3);
  const char* pa0 = Ab + (long)(wave * 8 + (lane >> 3)) * ldaB + (gchk << 4);
  const char* pb0 = Bb + (long)(wave * 8 + (lane >> 3)) * ldbB + (gchk << 4);
  char* lA = (char*)L + wave * 1024;
  char* lB = (char*)L + 65536 + wave * 1024;

  auto stA = [&](int tile, int h) {
    char* d = lA + (tile & 1) * 32768 + h * 16384;
    const char* s = pa0 + (long)h * 128 * ldaB + ((long)tile << 7);
    cp16(d, s);
    cp16(d + 8192, s + 64 * ldaB);
  };
  auto stB = [&](int tile, int h) {
    char* d = lB + (tile & 1) * 32768 + h * 16384;
    const char* s = pb0 + (long)h * 128 * ldbB + ((long)tile << 7);
    cp16(d, s);
    cp16(d + 8192, s + 64 * ldbB);
  };

  // Fragment LDS indices within a 128-row half (bf16x8 units): row m,
  // k-step s: idx = m*8 + ((s*4+quad) ^ (m&7)), m&7 = l15&7.
  int iaq[2][4], ibq[2][2];
#pragma unroll
  for (int s = 0; s < 2; ++s) {
#pragma unroll
    for (int i = 0; i < 4; ++i)
      iaq[s][i] = (wm * 64 + i * 16 + l15) * 8 + ((s * 4 + quad) ^ (l15 & 7));
#pragma unroll
    for (int j = 0; j < 2; ++j)
      ibq[s][j] = (wn * 32 + j * 16 + l15) * 8 + ((s * 4 + quad) ^ (l15 & 7));
  }

  f32x4 acc[2][2][4][2];
  {
    f32x4 zz = {0.f, 0.f, 0.f, 0.f};
#pragma unroll
    for (int mh = 0; mh < 2; ++mh)
#pragma unroll
      for (int nh = 0; nh < 2; ++nh)
#pragma unroll
        for (int i = 0; i < 4; ++i)
#pragma unroll
          for (int j = 0; j < 2; ++j) acc[mh][nh][i][j] = zz;
  }
  bf16x8 bfr[2][2][2];   // B fragments held across the K-tile (32 VGPR)

  // Prologue: tile0 fully + tile1 {Bl,Bh,Al}; vmcnt(6) completes tile0,
  // leaves tile1's 6 cp16 in flight (steady-state pattern expects Ah@ph0).
  stB(0, 0); stB(0, 1); stA(0, 0); stA(0, 1);
  stB(1, 0); stB(1, 1); stA(1, 0);
  asm volatile("s_waitcnt vmcnt(6)" ::: "memory");
  __builtin_amdgcn_s_barrier();

  // Steady state per iteration (tile t -> buf t&1):
  //   ph0: rq0 buf0 (+B read) | stage Ah(t+1)
  //   ph1: rq1 buf0           | stage Bl(t+2)   [B(t) died after ph0]
  //   ph2: rq2 buf0           | stage Bh(t+2)
  //   ph3: rq3 buf0           | stage Al(t+2); vmcnt(6) -> tile t+1 ready
  //   ph4: rq0 buf1 (+B read) | stage Ah(t+2)   [Ah(t) died after ph3]
  //   ph5: rq1 buf1           | stage Bl(t+3)
  //   ph6: rq2 buf1           | stage Bh(t+3)
  //   ph7: rq3 buf1           | stage Al(t+3); vmcnt(6) -> tile t+2 ready
  const int nt = g.K >> 6;   // 64-wide K-tiles; all K here are multiples of 128
  const int NI = nt >> 1;
  for (int it = 0; it < NI; ++it) {
    const int t = it * 2;
    const bool m2 = (t + 2) < nt;
    const bool m3 = (t + 3) < nt;
    PHASE(0, 0, 0, 1, stA(t + 1, 1), )
    PHASE(0, 2, 0, 0, if (m2) stB(t + 2, 0), )
    PHASE(1, 0, 0, 0, if (m2) stB(t + 2, 1), )
    PHASE(1, 2, 0, 0, if (m2) stA(t + 2, 0),
          if (m2) { asm volatile("s_waitcnt vmcnt(6)" ::: "memory"); }
          else    { asm volatile("s_waitcnt vmcnt(0)" ::: "memory"); })
    PHASE(0, 0, 1, 1, if (m2) stA(t + 2, 1), )
    PHASE(0, 2, 1, 0, if (m3) stB(t + 3, 0), )
    PHASE(1, 0, 1, 0, if (m3) stB(t + 3, 1), )
    PHASE(1, 2, 1, 0, if (m3) stA(t + 3, 0),
          if (m3)      { asm volatile("s_waitcnt vmcnt(6)" ::: "memory"); }
          else if (m2) { asm volatile("s_waitcnt vmcnt(0)" ::: "memory"); })
  }

  // Epilogue (swapped-operand layout): lane l15 = C row, regs = 4 cols.
  const long cbase = (long)bz * g.sC;
#pragma unroll
  for (int mh = 0; mh < 2; ++mh) {
#pragma unroll
    for (int i = 0; i < 4; ++i) {
      const int row = bx * 256 + mh * 128 + wm * 64 + i * 16 + l15;
      const float rbias = (g.mode == 2) ? g.bias[row] : 0.f;
#pragma unroll
      for (int nh = 0; nh < 2; ++nh) {
#pragma unroll
        for (int j = 0; j < 2; ++j) {
          const int colbase = by * 256 + nh * 128 + wn * 32 + j * 16 + quad * 4;
          float v[4];
#pragma unroll
          for (int r = 0; r < 4; ++r) v[r] = acc[mh][nh][i][j][r] * g.scale;
          if (g.mode == 1) {
            const float4 cb = *(const float4*)(g.bias + colbase);
            v[0] += cb.x; v[1] += cb.y; v[2] += cb.z; v[3] += cb.w;
          } else if (g.mode == 2) {
#pragma unroll
            for (int r = 0; r < 4; ++r) v[r] += rbias;
          }
          const long idx = cbase + (long)row * g.ldc + colbase;
          if (g.outf) {
            float4 st; st.x = v[0]; st.y = v[1]; st.z = v[2]; st.w = v[3];
            *(float4*)((float*)g.C + idx) = st;
          } else {
            uint2 st;
            st.x = (unsigned int)f2bf(v[0]) | ((unsigned int)f2bf(v[1]) << 16);
            st.y = (unsigned int)f2bf(v[2]) | ((unsigned int)f2bf(v[3]) << 16);
            *(uint2*)((u16*)g.C + idx) = st;
          }
        }
      }
    }
  }
}

// ---------------------------------------------------------------------------
// fp32 -> bf16 convert for two tensors in one launch. 8 elems/thread.
// ---------------------------------------------------------------------------
__global__ __launch_bounds__(256)
void cvt2_bf16_kernel(const float* __restrict__ sa, u16* __restrict__ da, int n8a,
                      const float* __restrict__ sb, u16* __restrict__ db, int n8b)
{
  int idx = blockIdx.x * 256 + threadIdx.x;
  const float* src; u16* dst; int i;
  if (idx < n8a) { src = sa; dst = da; i = idx; }
  else           { src = sb; dst = db; i = idx - n8a; if (i >= n8b) return; }
  const float4* s4 = (const float4*)src;
  float4 a = s4[i * 2], b = s4[i * 2 + 1];
  uint4 o;
  o.x = (unsigned int)f2bf(a.x) | ((unsigned int)f2bf(a.y) << 16);
  o.y = (unsigned int)f2bf(a.z) | ((unsigned int)f2bf(a.w) << 16);
  o.z = (unsigned int)f2bf(b.x) | ((unsigned int)f2bf(b.y) << 16);
  o.w = (unsigned int)f2bf(b.z) | ((unsigned int)f2bf(b.w) << 16);
  ((uint4*)dst)[i] = o;
}

// ---------------------------------------------------------------------------
// Transpose + convert six 768x768 fp32 weights ([in,out] -> bf16 [out,in]).
// ---------------------------------------------------------------------------
__global__ void transpose6_kernel(const float* s0, const float* s1, const float* s2,
                                  const float* s3, const float* s4, const float* s5,
                                  u16* d0, u16* d1, u16* d2,
                                  u16* d3, u16* d4, u16* d5)
{
  __shared__ float t[32][33];
  const float* src; u16* dst;
  switch (blockIdx.z) {
    case 0: src = s0; dst = d0; break;
    case 1: src = s1; dst = d1; break;
    case 2: src = s2; dst = d2; break;
    case 3: src = s3; dst = d3; break;
    case 4: src = s4; dst = d4; break;
    default: src = s5; dst = d5; break;
  }
  const int tx = threadIdx.x, ty = threadIdx.y;
  const int x = blockIdx.x * 32 + tx;
  const int y0 = blockIdx.y * 32;
#pragma unroll
  for (int j = 0; j < 32; j += 8) t[ty + j][tx] = src[(long)(y0 + ty + j) * 768 + x];
  __syncthreads();
  const int x2 = y0 + tx;
#pragma unroll
  for (int j = 0; j < 32; j += 8)
    dst[(long)(blockIdx.x * 32 + ty + j) * 768 + x2] = f2bf(t[tx][ty + j]);
}

// ---------------------------------------------------------------------------
// In-place row softmax (bf16) over S1 rows (4096 wide, 8192 rows) and S2 rows
// (2048 wide, 16384 rows), plus V2T evacuation copy, all in one launch.
// ---------------------------------------------------------------------------
template <int NV>
__device__ __forceinline__ void softmax_row(u16* row)
{
  __shared__ float red[8];
  const int tid  = threadIdx.x;
  const int lane = tid & 63;
  const int wave = tid >> 6;
  uint4* p4 = (uint4*)row;

  uint4 ld[NV / 8];
#pragma unroll
  for (int c = 0; c < NV / 8; ++c) ld[c] = p4[tid + c * 256];
  float v[NV];
#pragma unroll
  for (int c = 0; c < NV / 8; ++c) {
    unsigned int w[4] = {ld[c].x, ld[c].y, ld[c].z, ld[c].w};
#pragma unroll
    for (int q = 0; q < 4; ++q) {
      v[c * 8 + q * 2]     = bf2f((u16)(w[q] & 0xffffu));
      v[c * 8 + q * 2 + 1] = bf2f((u16)(w[q] >> 16));
    }
  }

  float m = -1e30f;
#pragma unroll
  for (int i = 0; i < NV; ++i) m = fmaxf(m, v[i]);
#pragma unroll
  for (int off = 32; off > 0; off >>= 1) m = fmaxf(m, __shfl_xor(m, off, 64));
  if (lane == 0) red[wave] = m;
  __syncthreads();
  m = fmaxf(fmaxf(red[0], red[1]), fmaxf(red[2], red[3]));

  float s = 0.f;
#pragma unroll
  for (int i = 0; i < NV; ++i) { v[i] = __expf(v[i] - m); s += v[i]; }
#pragma unroll
  for (int off = 32; off > 0; off >>= 1) s += __shfl_xor(s, off, 64);
  if (lane == 0) red[4 + wave] = s;
  __syncthreads();
  s = (red[4] + red[5]) + (red[6] + red[7]);
  const float inv = 1.0f / s;

#pragma unroll
  for (int c = 0; c < NV / 8; ++c) {
    unsigned int w[4];
#pragma unroll
    for (int q = 0; q < 4; ++q) {
      const u16 lo = f2bf(v[c * 8 + q * 2] * inv);
      const u16 hi = f2bf(v[c * 8 + q * 2 + 1] * inv);
      w[q] = (unsigned int)lo | ((unsigned int)hi << 16);
    }
    uint4 st; st.x = w[0]; st.y = w[1]; st.z = w[2]; st.w = w[3];
    p4[tid + c * 256] = st;
  }
}

__global__ __launch_bounds__(256)
void softmax_both_kernel(u16* S1, u16* S2, const u16* cpy_src, u16* cpy_dst)
{
  if (blockIdx.x < 8192) { softmax_row<16>(S1 + (long)blockIdx.x * 4096); return; }
  if (blockIdx.x < 24576) { softmax_row<8>(S2 + (long)(blockIdx.x - 8192) * 2048); return; }
  // copy blocks: 1536 blocks x 8 KB = 12,582,912 B (V2T out of out1)
  const long base = (long)(blockIdx.x - 24576) * 512 + threadIdx.x;
  const uint4* s = (const uint4*)cpy_src;
  uint4* d = (uint4*)cpy_dst;
  d[base] = s[base];
  d[base + 256] = s[base + 256];
}

// ---------------------------------------------------------------------------

static GemmDesc mkdesc(const void* A, const void* Bt, const float* bias, void* C,
                       long sA, long sB, long sC, int K, int lda, int ldb, int ldc,
                       int M, int N, int start, int mode, int outf, float scale)
{
  GemmDesc d;
  d.A = (const u16*)A; d.Bt = (const u16*)Bt; d.bias = bias; d.C = C;
  d.sA = sA; d.sB = sB; d.sC = sC;
  d.K = K; d.lda = lda; d.ldb = ldb; d.ldc = ldc;
  d.gx = M / 256; d.gy = N / 256; d.start = start;
  d.mode = mode; d.outf = outf; d.scale = scale;
  return d;
}

extern "C" void kernel_launch(void* const* d_in, const int* in_sizes, int n_in,
                              void* d_out, int out_size, void* d_ws, size_t ws_size,
                              hipStream_t stream)
{
  (void)in_sizes; (void)n_in; (void)out_size; (void)ws_size;
  const float* syn = (const float*)d_in[0];   // [4,4096,768] fp32
  const float* sem = (const float*)d_in[1];   // [4,2048,768] fp32
  const float* W[6]    = {(const float*)d_in[2], (const float*)d_in[4],  (const float*)d_in[6],
                          (const float*)d_in[8], (const float*)d_in[10], (const float*)d_in[12]};
  const float* bias[6] = {(const float*)d_in[3], (const float*)d_in[5],  (const float*)d_in[7],
                          (const float*)d_in[9], (const float*)d_in[11], (const float*)d_in[13]};
  float* out = (float*)d_out;

  // ws arena (u16 offsets). Peak use 85,983,232 u16 = 171.97 MB.
  u16* ws   = (u16*)d_ws;
  u16* S1   = ws;                       // [0, 33,554,432)
  u16* synb = ws;                       //   [0, 12,582,912)   dead after PROJ
  u16* semb = ws + 12582912;            //   [.., 18,874,368)  dead after PROJ
  u16* WT   = ws + 18874368;            //   [.., 22,413,312)  dead after PROJ
  u16* S2   = ws + 33554432;            // [.., 67,108,864)
  u16* V1T  = ws + 67108864;            // [.., 79,691,776)    until O1
  u16* Q1   = ws + 79691776;            // [.., 85,983,232)    dead after S1
  u16* V2Tc = ws + 79691776;            //   V2T copy target (over dead Q1)
  // parked in outputs:
  u16* K1  = (u16*)out;                 // out0: 12,582,912 u16, dead after S1
  u16* o1  = (u16*)(out + 6291456);     // out1 region base
  u16* Q2  = o1;                        // 12,582,912 u16, dead after S2
  u16* K2  = o1 + 12582912;             //  6,291,456 u16, dead after S2
  u16* V2T = o1 + 18874368;             //  6,291,456 u16, evacuated in D5

  const float SC = 0.036084391824351615f;  // 768^-0.5

  // D1) fp32 -> bf16 converts
  cvt2_bf16_kernel<<<dim3(9216), dim3(256), 0, stream>>>(
      syn, synb, 1572864, sem, semb, 786432);

  // D2) weight transpose+convert
  transpose6_kernel<<<dim3(24, 24, 6), dim3(32, 8, 1), 0, stream>>>(
      W[0], W[1], W[2], W[3], W[4], W[5],
      WT + 0 * 589824, WT + 1 * 589824, WT + 2 * 589824,
      WT + 3 * 589824, WT + 4 * 589824, WT + 5 * 589824);

  // D3) all six projections (864 blocks @ 256^2)
  {
    GemmPack p; p.nd = 6;
    p.d[0] = mkdesc(synb, WT + 1 * 589824, bias[1], K1, 0, 0, 0,     // K1 -> out0
                    768, 768, 768, 768, 16384, 768, 0, 1, 0, 1.f);
    p.d[1] = mkdesc(synb, WT + 3 * 589824, bias[3], Q2, 0, 0, 0,     // Q2 -> out1
                    768, 768, 768, 768, 16384, 768, 192, 1, 0, 1.f);
    p.d[2] = mkdesc(WT + 2 * 589824, synb, bias[2], V1T, 0, 0, 0,    // V1T -> ws
                    768, 768, 768, 16384, 768, 16384, 384, 2, 0, 1.f);
    p.d[3] = mkdesc(semb, WT + 0 * 589824, bias[0], Q1, 0, 0, 0,     // Q1 -> ws
                    768, 768, 768, 768, 8192, 768, 576, 1, 0, 1.f);
    p.d[4] = mkdesc(semb, WT + 4 * 589824, bias[4], K2, 0, 0, 0,     // K2 -> out1
                    768, 768, 768, 768, 8192, 768, 672, 1, 0, 1.f);
    p.d[5] = mkdesc(WT + 5 * 589824, semb, bias[5], V2T, 0, 0, 0,    // V2T -> out1
                    768, 768, 768, 8192, 768, 8192, 768, 2, 0, 1.f);
    gemm256_kernel<<<dim3(864), dim3(512), 0, stream>>>(p);
  }

  // D4) S1 + S2 (1024 blocks @ 256^2); S1 overwrites dead synb/semb/WT
  {
    GemmPack p; p.nd = 2;
    p.d[0] = mkdesc(Q1, K1, nullptr, S1,                             // [4][2048x4096]
                    1572864L, 3145728L, 8388608L,
                    768, 768, 768, 4096, 2048, 4096, 0, 0, 0, SC);
    p.d[1] = mkdesc(Q2, K2, nullptr, S2,                             // [4][4096x2048]
                    3145728L, 1572864L, 8388608L,
                    768, 768, 768, 2048, 4096, 2048, 512, 0, 0, SC);
    gemm256_kernel<<<dim3(1024), dim3(512), 0, stream>>>(p);
  }

  // D5) softmax over all S rows + V2T evacuation (one launch)
  softmax_both_kernel<<<dim3(26112), dim3(256), 0, stream>>>(S1, S2, V2T, V2Tc);

  // D6) O1 + O2 (288 blocks @ 256^2), fp32 -> d_out; long O1 blocks first
  {
    GemmPack p; p.nd = 2;
    p.d[0] = mkdesc(S1, V1T, nullptr, out,                           // [4][2048x768]
                    8388608L, 4096L, 1572864L,
                    4096, 4096, 16384, 768, 2048, 768, 0, 0, 1, 1.f);
    p.d[1] = mkdesc(S2, V2Tc, nullptr, out + 6291456,                // [4][4096x768]
                    8388608L, 2048L, 3145728L,
                    2048, 2048, 8192, 768, 4096, 768, 96, 0, 1, 1.f);
    gemm256_kernel<<<dim3(288), dim3(512), 0, stream>>>(p);
  }
}